// Round 1
// baseline (177.747 us; speedup 1.0000x reference)
//
#include <hip/hip_runtime.h>
#include <hip/hip_fp16.h>

#define H0 200
#define W0 304
#define H1 100
#define W1 152
#define H2 50
#define W2 76
#define CPL 256   // channels per level
#define CTOT 768
#define OH 7
#define OW 7
#define NPOS 49
#define SROW2 772  // sout row stride (floats): 768 + 4 pad

#define P0 (H0*W0)   // 60800
#define P1 (H1*W1)   // 15200
#define P2 (H2*W2)   // 3800
#define T0_OFF ((size_t)0)
#define T1_OFF ((size_t)P0*CPL)
#define T2_OFF ((size_t)P0*CPL + (size_t)P1*CPL)
#define WS_ELEMS ((size_t)P0*CPL + (size_t)P1*CPL + (size_t)P2*CPL)
#define WS_BYTES (WS_ELEMS * 2)   // fp16 workspace: 40,857,600 B

__device__ __forceinline__ float hat01(float d) {
    return fmaxf(0.0f, 1.0f - fabsf(d));
}

__device__ __forceinline__ unsigned short f2h_rne(float x) {
    return __half_as_ushort(__float2half_rn(x));
}

// ------------- Stage 1: fused [C][P] fp32 -> [P][C] fp16 transpose ----------
__global__ void __launch_bounds__(256)
transpose_all_kernel(const float* __restrict__ f0, const float* __restrict__ f1,
                     const float* __restrict__ f2,
                     unsigned short* __restrict__ T0,
                     unsigned short* __restrict__ T1,
                     unsigned short* __restrict__ T2, int n0, int n01) {
    __shared__ unsigned short tile[64][72];   // [p_local][c_local]
    int b = blockIdx.x;
    const float* in; unsigned short* outp; int P; int rel;
    if (b < n0)       { in = f0; outp = T0; P = P0; rel = b; }
    else if (b < n01) { in = f1; outp = T1; P = P1; rel = b - n0; }
    else              { in = f2; outp = T2; P = P2; rel = b - n01; }
    int p0 = (rel >> 2) * 64;
    int c0 = (rel & 3) * 64;

    int q = threadIdx.x & 15;     // p-quad
    int r = threadIdx.x >> 4;     // 0..15 (c)
    bool full = (p0 + 64 <= P);
#pragma unroll
    for (int i = 0; i < 4; ++i) {
        int c = c0 + r + 16 * i;
        int p = p0 + 4 * q;
        float4 v;
        if (full) {
            v = *(const float4*)(in + (size_t)c * P + p);
        } else {
            v.x = (p + 0 < P) ? in[(size_t)c * P + p + 0] : 0.0f;
            v.y = (p + 1 < P) ? in[(size_t)c * P + p + 1] : 0.0f;
            v.z = (p + 2 < P) ? in[(size_t)c * P + p + 2] : 0.0f;
            v.w = (p + 3 < P) ? in[(size_t)c * P + p + 3] : 0.0f;
        }
        tile[4 * q + 0][r + 16 * i] = f2h_rne(v.x);
        tile[4 * q + 1][r + 16 * i] = f2h_rne(v.y);
        tile[4 * q + 2][r + 16 * i] = f2h_rne(v.z);
        tile[4 * q + 3][r + 16 * i] = f2h_rne(v.w);
    }
    __syncthreads();
    int q8 = threadIdx.x & 7;     // c-octet
    int r8 = threadIdx.x >> 3;    // 0..31 (p)
#pragma unroll
    for (int i = 0; i < 2; ++i) {
        int p = p0 + r8 + 32 * i;
        if (p < P) {
            uint4 w = *(const uint4*)&tile[r8 + 32 * i][8 * q8];
            *(uint4*)(outp + (size_t)p * CPL + c0 + 8 * q8) = w;
        }
    }
}

// ------------- Stage 2: channels-last RoIAlign, one output row per block ----
// Block = (n, oh): all 3 levels for one 7-wide output row -> identical work
// per block (zero inter-block imbalance). 256 threads = 4 waves; wave wv
// handles ow pair {2wv, 2wv+1} via half-waves (wave 3 half 1 duplicates ow=6,
// benign). Lane carries 8 channels (uint4 = 4x half2); x-taps accumulate with
// v_pk_fma_f16, y-fold with fma_mix into fp32.
template<int TY, int TX>
__device__ __forceinline__ void proc_level(const __half* __restrict__ T,
                                           const int (*__restrict__ sidx)[6],
                                           const float (*__restrict__ sw)[6],
                                           float* __restrict__ srow,
                                           unsigned co, int ow) {
    unsigned yo[TY]; float yw[TY];
#pragma unroll
    for (int j = 0; j < TY; ++j) { yo[j] = (unsigned)sidx[0][j]; yw[j] = sw[0][j]; }
    unsigned xo[TX]; __half2 xw2[TX];
#pragma unroll
    for (int j = 0; j < TX; ++j) {
        xo[j] = (unsigned)sidx[1 + ow][j];
        xw2[j] = __float2half2_rn(sw[1 + ow][j]);
    }
    float a0 = 0.f, a1 = 0.f, a2 = 0.f, a3 = 0.f;
    float a4 = 0.f, a5 = 0.f, a6 = 0.f, a7 = 0.f;
#pragma unroll
    for (int a = 0; a < TY; ++a) {
        unsigned ro = yo[a] + co;
        __half2 r0 = __float2half2_rn(0.0f);
        __half2 r1 = r0, r2 = r0, r3 = r0;
#pragma unroll
        for (int b = 0; b < TX; ++b) {
            uint4 v = *(const uint4*)(T + (ro + xo[b]));
            r0 = __hfma2(xw2[b], *(const __half2*)&v.x, r0);
            r1 = __hfma2(xw2[b], *(const __half2*)&v.y, r1);
            r2 = __hfma2(xw2[b], *(const __half2*)&v.z, r2);
            r3 = __hfma2(xw2[b], *(const __half2*)&v.w, r3);
        }
        float wa = yw[a];
        a0 = fmaf(wa, __low2float(r0), a0);  a1 = fmaf(wa, __high2float(r0), a1);
        a2 = fmaf(wa, __low2float(r1), a2);  a3 = fmaf(wa, __high2float(r1), a3);
        a4 = fmaf(wa, __low2float(r2), a4);  a5 = fmaf(wa, __high2float(r2), a5);
        a6 = fmaf(wa, __low2float(r3), a6);  a7 = fmaf(wa, __high2float(r3), a7);
    }
    float4 o0, o1;
    o0.x = a0 * 0.25f; o0.y = a1 * 0.25f; o0.z = a2 * 0.25f; o0.w = a3 * 0.25f;
    o1.x = a4 * 0.25f; o1.y = a5 * 0.25f; o1.z = a6 * 0.25f; o1.w = a7 * 0.25f;
    *(float4*)(srow + co) = o0;
    *(float4*)(srow + co + 4) = o1;
}

__global__ void __launch_bounds__(256, 6)
roi_align_row_kernel(const unsigned short* __restrict__ T0p,
                     const unsigned short* __restrict__ T1p,
                     const unsigned short* __restrict__ T2p,
                     const float* __restrict__ boxes,
                     const int* __restrict__ img_h_p,
                     const int* __restrict__ img_w_p,
                     float* __restrict__ out) {
    __shared__ float sout[OW][SROW2];      // [ow][c] for this oh-row
    __shared__ int   s_idx[3][8][6];       // [lev][0=y(oh) | 1+ow=x][tap]
    __shared__ float s_w[3][8][6];

    const int n = blockIdx.x;
    const int oh = blockIdx.y;
    const int tid = threadIdx.x;

    if (tid < 24) {
        int lev = tid >> 3;
        int o8 = tid & 7;
        int axis = (o8 > 0) ? 1 : 0;       // 0 = y (this oh), 1 = x (ow = o8-1)
        int o = axis ? (o8 - 1) : oh;
        int Hc = (lev == 0) ? H0 : (lev == 1) ? H1 : H2;
        int Wc = (lev == 0) ? W0 : (lev == 1) ? W1 : W2;
        float inv_s = (lev == 0) ? 1.0f : (lev == 1) ? 0.5f : 0.25f;
        float sx = (float)W0 / (float)img_w_p[0];
        float sy = (float)H0 / (float)img_h_p[0];
        float a1v, bs; int Hf, Hca, mul;
        if (axis) {
            a1v = boxes[n * 4 + 0] * sx;
            float a2v = boxes[n * 4 + 2] * sx;
            bs = fmaxf(a2v - a1v, 1.0f) * (1.0f / (float)OW);
            Hf = W0; Hca = Wc; mul = 1;
        } else {
            a1v = boxes[n * 4 + 1] * sy;
            float a2v = boxes[n * 4 + 3] * sy;
            bs = fmaxf(a2v - a1v, 1.0f) * (1.0f / (float)OH);
            Hf = H0; Hca = Hc; mul = Wc;
        }
        int idx[6]; float w[6];
#pragma unroll
        for (int j = 0; j < 6; ++j) { idx[j] = 0; w[j] = 0.0f; }
        if (lev == 0) {
#pragma unroll
            for (int r2 = 0; r2 < 2; ++r2) {
                float Y = a1v + ((float)o + 0.25f + 0.5f * (float)r2) * bs;
                float v = (Y >= -1.0f && Y <= (float)Hf) ? 1.0f : 0.0f;
                float Yc = fminf(fmaxf(Y, 0.0f), (float)(Hf - 1));
                int y0 = (int)Yc; float lf = Yc - (float)y0;
                idx[2 * r2]     = y0;                  w[2 * r2]     = (1.0f - lf) * v;
                idx[2 * r2 + 1] = min(y0 + 1, Hf - 1); w[2 * r2 + 1] = lf * v;
            }
        } else {
            int bases[2]; float w3[2][3];
#pragma unroll
            for (int r2 = 0; r2 < 2; ++r2) {
                float Y = a1v + ((float)o + 0.25f + 0.5f * (float)r2) * bs;
                float v = (Y >= -1.0f && Y <= (float)Hf) ? 1.0f : 0.0f;
                float Yc = fminf(fmaxf(Y, 0.0f), (float)(Hf - 1));
                int y0 = (int)Yc; float lf = Yc - (float)y0; float hf = 1.0f - lf;
                int yf1 = min(y0 + 1, Hf - 1);
                float yc0 = fminf(fmaxf(((float)y0 + 0.5f) * inv_s - 0.5f, 0.0f), (float)(Hca - 1));
                float yc1 = fminf(fmaxf(((float)yf1 + 0.5f) * inv_s - 0.5f, 0.0f), (float)(Hca - 1));
                int b2 = (int)yc0;
                bases[r2] = b2;
#pragma unroll
                for (int t2 = 0; t2 < 3; ++t2) {
                    float j2 = (float)(b2 + t2);
                    w3[r2][t2] = v * (hf * hat01(yc0 - j2) + lf * hat01(yc1 - j2));
                }
            }
            int dmax = (lev == 1) ? 3 : 2;   // geometry: box<=272px -> gap<=2.43/1.21
            int d = min(max(bases[1] - bases[0], 0), dmax);
            w[0] += w3[0][0]; w[1] += w3[0][1]; w[2] += w3[0][2];
            w[d] += w3[1][0]; w[d + 1] += w3[1][1]; w[d + 2] += w3[1][2];
#pragma unroll
            for (int j = 0; j < 6; ++j) idx[j] = min(bases[0] + j, Hca - 1);
        }
        // pre-scale to element offset (row stride incl. CPL; col stride = CPL)
#pragma unroll
        for (int j = 0; j < 6; ++j) { s_idx[lev][o8][j] = idx[j] * mul * CPL; s_w[lev][o8][j] = w[j]; }
    }
    __syncthreads();

    const int lane = tid & 63;
    const int wv = tid >> 6;            // 0..3
    const int half = lane >> 5;         // half-wave -> even/odd ow of pair
    const int l = lane & 31;            // 0..31, 8 channels each
    int ow = 2 * wv + half;
    ow = (ow > OW - 1) ? (OW - 1) : ow; // wave 3 half 1: benign duplicate of ow=6
    unsigned co = (unsigned)(l * 8);
    float* srow = &sout[ow][0];

    proc_level<4, 4>((const __half*)T0p, s_idx[0], s_w[0], srow,           co, ow);
    proc_level<6, 6>((const __half*)T1p, s_idx[1], s_w[1], srow + CPL,     co, ow);
    proc_level<5, 5>((const __half*)T2p, s_idx[2], s_w[2], srow + 2 * CPL, co, ow);
    __syncthreads();

    // out[n][c][oh*7 + ow]
    size_t obase = (size_t)n * CTOT * NPOS + (size_t)oh * OW;
    for (int i2 = tid; i2 < CTOT * OW; i2 += 256) {
        int c = i2 / OW;
        int p = i2 - c * OW;
        out[obase + (size_t)c * NPOS + p] = sout[p][c];
    }
}

// ---------------- Fallback (R1 kernel) if ws too small ----------------------
__device__ __forceinline__ void axis_w3_fb(int yf0, int Hf, int Hc, float inv_s,
                                           float lf, int& base, float* w) {
    int yf1 = min(yf0 + 1, Hf - 1);
    float hf = 1.0f - lf;
    float yc0 = fminf(fmaxf(((float)yf0 + 0.5f) * inv_s - 0.5f, 0.0f), (float)(Hc - 1));
    float yc1 = fminf(fmaxf(((float)yf1 + 0.5f) * inv_s - 0.5f, 0.0f), (float)(Hc - 1));
    base = (int)yc0;
#pragma unroll
    for (int r = 0; r < 3; ++r) {
        float j = (float)(base + r);
        w[r] = hf * hat01(yc0 - j) + lf * hat01(yc1 - j);
    }
}

__global__ void __launch_bounds__(256)
roi_align_fused_fb_kernel(const float* __restrict__ f0,
                          const float* __restrict__ f1,
                          const float* __restrict__ f2,
                          const float* __restrict__ boxes,
                          const int* __restrict__ img_h_p,
                          const int* __restrict__ img_w_p,
                          float* __restrict__ out,
                          int total) {
    int i = blockIdx.x * blockDim.x + threadIdx.x;
    if (i >= total) return;
    int ow = i % OW;
    int t = i / OW;
    int oh = t % OH; t /= OH;
    int c = t % CTOT;
    int n = t / CTOT;
    float sx = (float)W0 / (float)img_w_p[0];
    float sy = (float)H0 / (float)img_h_p[0];
    float bx1 = boxes[n * 4 + 0] * sx;
    float by1 = boxes[n * 4 + 1] * sy;
    float bw = fmaxf(boxes[n * 4 + 2] * sx - bx1, 1.0f) / OW;
    float bh = fmaxf(boxes[n * 4 + 3] * sy - by1, 1.0f) / OH;
    int level = c >> 8;
    int cl = c & (CPL - 1);
    const float* f;
    int Hc, Wc; float inv_s;
    if (level == 0)      { f = f0 + (size_t)cl * P0; Hc = H0; Wc = W0; inv_s = 1.0f;  }
    else if (level == 1) { f = f1 + (size_t)cl * P1; Hc = H1; Wc = W1; inv_s = 0.5f;  }
    else                 { f = f2 + (size_t)cl * P2; Hc = H2; Wc = W2; inv_s = 0.25f; }
    float acc = 0.0f;
#pragma unroll
    for (int ry = 0; ry < 2; ++ry) {
        float Y = by1 + ((float)oh + 0.25f + 0.5f * ry) * bh;
        bool vy = (Y >= -1.0f) && (Y <= (float)H0);
        float Yc = fminf(fmaxf(Y, 0.0f), (float)(H0 - 1));
        int y0 = (int)Yc;
        float ly = Yc - (float)y0;
#pragma unroll
        for (int rx = 0; rx < 2; ++rx) {
            float X = bx1 + ((float)ow + 0.25f + 0.5f * rx) * bw;
            bool vx = (X >= -1.0f) && (X <= (float)W0);
            float Xc = fminf(fmaxf(X, 0.0f), (float)(W0 - 1));
            int x0 = (int)Xc;
            float lx = Xc - (float)x0;
            float v;
            if (level == 0) {
                int y1i = min(y0 + 1, H0 - 1), x1i = min(x0 + 1, W0 - 1);
                float hy = 1.0f - ly, hx = 1.0f - lx;
                float v00 = f[y0 * W0 + x0],  v01 = f[y0 * W0 + x1i];
                float v10 = f[y1i * W0 + x0], v11 = f[y1i * W0 + x1i];
                v = hy * (hx * v00 + lx * v01) + ly * (hx * v10 + lx * v11);
            } else {
                int yb, xb; float wy[3], wxl[3];
                axis_w3_fb(y0, H0, Hc, inv_s, ly, yb, wy);
                axis_w3_fb(x0, W0, Wc, inv_s, lx, xb, wxl);
                v = 0.0f;
#pragma unroll
                for (int a = 0; a < 3; ++a) {
                    int row = min(yb + a, Hc - 1) * Wc;
                    float s = 0.0f;
#pragma unroll
                    for (int b = 0; b < 3; ++b)
                        s += wxl[b] * f[row + min(xb + b, Wc - 1)];
                    v += wy[a] * s;
                }
            }
            if (vy && vx) acc += v;
        }
    }
    out[i] = acc * 0.25f;
}

// ---------------- launch ----------------------------------------------------
extern "C" void kernel_launch(void* const* d_in, const int* in_sizes, int n_in,
                              void* d_out, int out_size, void* d_ws, size_t ws_size,
                              hipStream_t stream) {
    const float* f0    = (const float*)d_in[0];
    const float* f1    = (const float*)d_in[1];
    const float* f2    = (const float*)d_in[2];
    const float* boxes = (const float*)d_in[3];
    const int* img_h_p = (const int*)d_in[4];
    const int* img_w_p = (const int*)d_in[5];
    float* out = (float*)d_out;
    int N = in_sizes[3] / 4;

    if (ws_size >= WS_BYTES) {
        unsigned short* ws = (unsigned short*)d_ws;
        unsigned short* T0 = ws + T0_OFF;
        unsigned short* T1 = ws + T1_OFF;
        unsigned short* T2 = ws + T2_OFF;
        int n0 = ((P0 + 63) / 64) * 4;   // 3800
        int n1 = ((P1 + 63) / 64) * 4;   // 952
        int n2 = ((P2 + 63) / 64) * 4;   // 240
        transpose_all_kernel<<<n0 + n1 + n2, 256, 0, stream>>>(
            f0, f1, f2, T0, T1, T2, n0, n0 + n1);
        roi_align_row_kernel<<<dim3(N, OH), 256, 0, stream>>>(
            T0, T1, T2, boxes, img_h_p, img_w_p, out);
    } else {
        int total = N * CTOT * OH * OW;
        roi_align_fused_fb_kernel<<<(total + 255) / 256, 256, 0, stream>>>(
            f0, f1, f2, boxes, img_h_p, img_w_p, out, total);
    }
}

// Round 2
// 160.799 us; speedup vs baseline: 1.1054x; 1.1054x over previous
//
#include <hip/hip_runtime.h>
#include <hip/hip_fp16.h>

#define H0 200
#define W0 304
#define H1 100
#define W1 152
#define H2 50
#define W2 76
#define CPL 256   // channels per level
#define CTOT 768
#define OH 7
#define OW 7
#define NPOS 49
#define CBLK 128   // channels per stage-2 block
#define SROWP 131  // sout row stride (floats): 128 + 3 pad (131%32=3, coprime)

#define P0 (H0*W0)   // 60800
#define P1 (H1*W1)   // 15200
#define P2 (H2*W2)   // 3800
#define T0_OFF ((size_t)0)
#define T1_OFF ((size_t)P0*CPL)
#define T2_OFF ((size_t)P0*CPL + (size_t)P1*CPL)
#define WS_ELEMS ((size_t)P0*CPL + (size_t)P1*CPL + (size_t)P2*CPL)
#define WS_BYTES (WS_ELEMS * 2)   // fp16 workspace: 40,857,600 B

__device__ __forceinline__ float hat01(float d) {
    return fmaxf(0.0f, 1.0f - fabsf(d));
}

__device__ __forceinline__ unsigned short f2h_rne(float x) {
    return __half_as_ushort(__float2half_rn(x));
}

// ------------- Stage 1: fused [C][P] fp32 -> [P][C] fp16 transpose ----------
__global__ void __launch_bounds__(256)
transpose_all_kernel(const float* __restrict__ f0, const float* __restrict__ f1,
                     const float* __restrict__ f2,
                     unsigned short* __restrict__ T0,
                     unsigned short* __restrict__ T1,
                     unsigned short* __restrict__ T2, int n0, int n01) {
    __shared__ unsigned short tile[64][72];   // [p_local][c_local]
    int b = blockIdx.x;
    const float* in; unsigned short* outp; int P; int rel;
    if (b < n0)       { in = f0; outp = T0; P = P0; rel = b; }
    else if (b < n01) { in = f1; outp = T1; P = P1; rel = b - n0; }
    else              { in = f2; outp = T2; P = P2; rel = b - n01; }
    int p0 = (rel >> 2) * 64;
    int c0 = (rel & 3) * 64;

    int q = threadIdx.x & 15;     // p-quad
    int r = threadIdx.x >> 4;     // 0..15 (c)
    bool full = (p0 + 64 <= P);
#pragma unroll
    for (int i = 0; i < 4; ++i) {
        int c = c0 + r + 16 * i;
        int p = p0 + 4 * q;
        float4 v;
        if (full) {
            v = *(const float4*)(in + (size_t)c * P + p);
        } else {
            v.x = (p + 0 < P) ? in[(size_t)c * P + p + 0] : 0.0f;
            v.y = (p + 1 < P) ? in[(size_t)c * P + p + 1] : 0.0f;
            v.z = (p + 2 < P) ? in[(size_t)c * P + p + 2] : 0.0f;
            v.w = (p + 3 < P) ? in[(size_t)c * P + p + 3] : 0.0f;
        }
        tile[4 * q + 0][r + 16 * i] = f2h_rne(v.x);
        tile[4 * q + 1][r + 16 * i] = f2h_rne(v.y);
        tile[4 * q + 2][r + 16 * i] = f2h_rne(v.z);
        tile[4 * q + 3][r + 16 * i] = f2h_rne(v.w);
    }
    __syncthreads();
    int q8 = threadIdx.x & 7;     // c-octet
    int r8 = threadIdx.x >> 3;    // 0..31 (p)
#pragma unroll
    for (int i = 0; i < 2; ++i) {
        int p = p0 + r8 + 32 * i;
        if (p < P) {
            uint4 w = *(const uint4*)&tile[r8 + 32 * i][8 * q8];
            *(uint4*)(outp + (size_t)p * CPL + c0 + 8 * q8) = w;
        }
    }
}

// ------------- Stage 2: channels-last RoIAlign, 128-ch slab per block -------
// Block = (n, j), j in [0,6): level = j>>1, channel half = j&1. Each block
// computes ALL 49 positions for its 128 channels -> output slab
// out[n][cbase..cbase+128][0..49] is fully contiguous (coalesced full-line
// writes; fixes R1's 2x write amplification). 16 lanes x 8 ch cover 128 ch;
// 16 positions in flight; pos += 16 loop (no duplicate work). Grid 1536
// blocks @ ~25.7KB LDS -> 6 blocks/CU, backfill absorbs level imbalance.
template<int TY, int TX>
__device__ __forceinline__ void tap_loop(const __half* __restrict__ Tc,
                                         const int (*__restrict__ s_idx)[6],
                                         const float (*__restrict__ s_w)[6],
                                         float (*__restrict__ sout)[SROWP],
                                         int grp, int col) {
    for (int pos = grp; pos < NPOS; pos += 16) {
        int oh = pos / 7;
        int ow = pos - oh * 7;
        unsigned yo[TY]; float yw[TY];
#pragma unroll
        for (int j = 0; j < TY; ++j) { yo[j] = (unsigned)s_idx[oh][j];     yw[j] = s_w[oh][j]; }
        unsigned xo[TX]; __half2 xw2[TX];
#pragma unroll
        for (int j = 0; j < TX; ++j) {
            xo[j] = (unsigned)s_idx[7 + ow][j];
            xw2[j] = __float2half2_rn(s_w[7 + ow][j]);
        }
        float a0 = 0.f, a1 = 0.f, a2 = 0.f, a3 = 0.f;
        float a4 = 0.f, a5 = 0.f, a6 = 0.f, a7 = 0.f;
#pragma unroll
        for (int a = 0; a < TY; ++a) {
            unsigned ro = yo[a];
            __half2 r0 = __float2half2_rn(0.0f);
            __half2 r1 = r0, r2 = r0, r3 = r0;
#pragma unroll
            for (int b = 0; b < TX; ++b) {
                uint4 v = *(const uint4*)(Tc + (ro + xo[b]));
                r0 = __hfma2(xw2[b], *(const __half2*)&v.x, r0);
                r1 = __hfma2(xw2[b], *(const __half2*)&v.y, r1);
                r2 = __hfma2(xw2[b], *(const __half2*)&v.z, r2);
                r3 = __hfma2(xw2[b], *(const __half2*)&v.w, r3);
            }
            float wa = yw[a];
            a0 = fmaf(wa, __low2float(r0), a0);  a1 = fmaf(wa, __high2float(r0), a1);
            a2 = fmaf(wa, __low2float(r1), a2);  a3 = fmaf(wa, __high2float(r1), a3);
            a4 = fmaf(wa, __low2float(r2), a4);  a5 = fmaf(wa, __high2float(r2), a5);
            a6 = fmaf(wa, __low2float(r3), a6);  a7 = fmaf(wa, __high2float(r3), a7);
        }
        float4 o0, o1;
        o0.x = a0 * 0.25f; o0.y = a1 * 0.25f; o0.z = a2 * 0.25f; o0.w = a3 * 0.25f;
        o1.x = a4 * 0.25f; o1.y = a5 * 0.25f; o1.z = a6 * 0.25f; o1.w = a7 * 0.25f;
        *(float4*)(&sout[pos][col])     = o0;
        *(float4*)(&sout[pos][col + 4]) = o1;
    }
}

__global__ void __launch_bounds__(256, 6)
roi_align_cl6_kernel(const unsigned short* __restrict__ T0p,
                     const unsigned short* __restrict__ T1p,
                     const unsigned short* __restrict__ T2p,
                     const float* __restrict__ boxes,
                     const int* __restrict__ img_h_p,
                     const int* __restrict__ img_w_p,
                     float* __restrict__ out) {
    __shared__ float sout[NPOS][SROWP];    // [pos][c_local]
    __shared__ int   s_idx[14][6];         // [0..6]=y(oh), [7..13]=x(ow)
    __shared__ float s_w[14][6];

    const int n = blockIdx.x;
    const int j = blockIdx.y;              // 0..5
    const int lev = j >> 1;
    const int chalf = j & 1;
    const int tid = threadIdx.x;

    const unsigned short* T; int Hc, Wc; float inv_s;
    if (lev == 0)      { T = T0p; Hc = H0; Wc = W0; inv_s = 1.0f;  }
    else if (lev == 1) { T = T1p; Hc = H1; Wc = W1; inv_s = 0.5f;  }
    else               { T = T2p; Hc = H2; Wc = W2; inv_s = 0.25f; }

    if (tid < 14) {
        int axis = (tid >= 7) ? 1 : 0;     // 0 = y, 1 = x
        int o = tid - axis * 7;
        float sx = (float)W0 / (float)img_w_p[0];
        float sy = (float)H0 / (float)img_h_p[0];
        float a1v, bs; int Hf, Hca, mul;
        if (axis) {
            a1v = boxes[n * 4 + 0] * sx;
            float a2v = boxes[n * 4 + 2] * sx;
            bs = fmaxf(a2v - a1v, 1.0f) * (1.0f / (float)OW);
            Hf = W0; Hca = Wc; mul = 1;
        } else {
            a1v = boxes[n * 4 + 1] * sy;
            float a2v = boxes[n * 4 + 3] * sy;
            bs = fmaxf(a2v - a1v, 1.0f) * (1.0f / (float)OH);
            Hf = H0; Hca = Hc; mul = Wc;
        }
        int idx[6]; float w[6];
#pragma unroll
        for (int t = 0; t < 6; ++t) { idx[t] = 0; w[t] = 0.0f; }
        if (lev == 0) {
#pragma unroll
            for (int r2 = 0; r2 < 2; ++r2) {
                float Y = a1v + ((float)o + 0.25f + 0.5f * (float)r2) * bs;
                float v = (Y >= -1.0f && Y <= (float)Hf) ? 1.0f : 0.0f;
                float Yc = fminf(fmaxf(Y, 0.0f), (float)(Hf - 1));
                int y0 = (int)Yc; float lf = Yc - (float)y0;
                idx[2 * r2]     = y0;                  w[2 * r2]     = (1.0f - lf) * v;
                idx[2 * r2 + 1] = min(y0 + 1, Hf - 1); w[2 * r2 + 1] = lf * v;
            }
        } else {
            int bases[2]; float w3[2][3];
#pragma unroll
            for (int r2 = 0; r2 < 2; ++r2) {
                float Y = a1v + ((float)o + 0.25f + 0.5f * (float)r2) * bs;
                float v = (Y >= -1.0f && Y <= (float)Hf) ? 1.0f : 0.0f;
                float Yc = fminf(fmaxf(Y, 0.0f), (float)(Hf - 1));
                int y0 = (int)Yc; float lf = Yc - (float)y0; float hf = 1.0f - lf;
                int yf1 = min(y0 + 1, Hf - 1);
                float yc0 = fminf(fmaxf(((float)y0 + 0.5f) * inv_s - 0.5f, 0.0f), (float)(Hca - 1));
                float yc1 = fminf(fmaxf(((float)yf1 + 0.5f) * inv_s - 0.5f, 0.0f), (float)(Hca - 1));
                int b2 = (int)yc0;
                bases[r2] = b2;
#pragma unroll
                for (int t2 = 0; t2 < 3; ++t2) {
                    float j2 = (float)(b2 + t2);
                    w3[r2][t2] = v * (hf * hat01(yc0 - j2) + lf * hat01(yc1 - j2));
                }
            }
            int dmax = (lev == 1) ? 3 : 2;   // geometry: box<=272px -> gap<=2.43/1.21
            int d = min(max(bases[1] - bases[0], 0), dmax);
            w[0] += w3[0][0]; w[1] += w3[0][1]; w[2] += w3[0][2];
            w[d] += w3[1][0]; w[d + 1] += w3[1][1]; w[d + 2] += w3[1][2];
#pragma unroll
            for (int t = 0; t < 6; ++t) idx[t] = min(bases[0] + t, Hca - 1);
        }
        // pre-scale to element offset in T (row stride Wc*CPL; col stride CPL)
#pragma unroll
        for (int t = 0; t < 6; ++t) { s_idx[tid][t] = idx[t] * mul * CPL; s_w[tid][t] = w[t]; }
    }
    __syncthreads();

    const int grp = tid >> 4;              // 0..15: position group
    const int l16 = tid & 15;              // 0..15: 8 channels each
    const int col = l16 * 8;               // local channel within the 128-slab
    const __half* Tc = (const __half*)T + (chalf * CBLK + col);

    if (lev == 0)      tap_loop<4, 4>(Tc, s_idx, s_w, sout, grp, col);
    else if (lev == 1) tap_loop<6, 6>(Tc, s_idx, s_w, sout, grp, col);
    else               tap_loop<5, 5>(Tc, s_idx, s_w, sout, grp, col);
    __syncthreads();

    // Writeback: out[n][lev*256 + chalf*128 + c][p], contiguous 128*49 floats.
    size_t obase = (size_t)n * CTOT * NPOS + (size_t)(lev * CPL + chalf * CBLK) * NPOS;
    int c = tid / NPOS;
    int p = tid - c * NPOS;
    for (int i = tid; i < CBLK * NPOS; i += 256) {
        out[obase + i] = sout[p][c];
        c += 5; p += 11;                   // 256 = 5*49 + 11
        if (p >= NPOS) { p -= NPOS; ++c; }
    }
}

// ---------------- Fallback (R1 kernel) if ws too small ----------------------
__device__ __forceinline__ void axis_w3_fb(int yf0, int Hf, int Hc, float inv_s,
                                           float lf, int& base, float* w) {
    int yf1 = min(yf0 + 1, Hf - 1);
    float hf = 1.0f - lf;
    float yc0 = fminf(fmaxf(((float)yf0 + 0.5f) * inv_s - 0.5f, 0.0f), (float)(Hc - 1));
    float yc1 = fminf(fmaxf(((float)yf1 + 0.5f) * inv_s - 0.5f, 0.0f), (float)(Hc - 1));
    base = (int)yc0;
#pragma unroll
    for (int r = 0; r < 3; ++r) {
        float j = (float)(base + r);
        w[r] = hf * hat01(yc0 - j) + lf * hat01(yc1 - j);
    }
}

__global__ void __launch_bounds__(256)
roi_align_fused_fb_kernel(const float* __restrict__ f0,
                          const float* __restrict__ f1,
                          const float* __restrict__ f2,
                          const float* __restrict__ boxes,
                          const int* __restrict__ img_h_p,
                          const int* __restrict__ img_w_p,
                          float* __restrict__ out,
                          int total) {
    int i = blockIdx.x * blockDim.x + threadIdx.x;
    if (i >= total) return;
    int ow = i % OW;
    int t = i / OW;
    int oh = t % OH; t /= OH;
    int c = t % CTOT;
    int n = t / CTOT;
    float sx = (float)W0 / (float)img_w_p[0];
    float sy = (float)H0 / (float)img_h_p[0];
    float bx1 = boxes[n * 4 + 0] * sx;
    float by1 = boxes[n * 4 + 1] * sy;
    float bw = fmaxf(boxes[n * 4 + 2] * sx - bx1, 1.0f) / OW;
    float bh = fmaxf(boxes[n * 4 + 3] * sy - by1, 1.0f) / OH;
    int level = c >> 8;
    int cl = c & (CPL - 1);
    const float* f;
    int Hc, Wc; float inv_s;
    if (level == 0)      { f = f0 + (size_t)cl * P0; Hc = H0; Wc = W0; inv_s = 1.0f;  }
    else if (level == 1) { f = f1 + (size_t)cl * P1; Hc = H1; Wc = W1; inv_s = 0.5f;  }
    else                 { f = f2 + (size_t)cl * P2; Hc = H2; Wc = W2; inv_s = 0.25f; }
    float acc = 0.0f;
#pragma unroll
    for (int ry = 0; ry < 2; ++ry) {
        float Y = by1 + ((float)oh + 0.25f + 0.5f * ry) * bh;
        bool vy = (Y >= -1.0f) && (Y <= (float)H0);
        float Yc = fminf(fmaxf(Y, 0.0f), (float)(H0 - 1));
        int y0 = (int)Yc;
        float ly = Yc - (float)y0;
#pragma unroll
        for (int rx = 0; rx < 2; ++rx) {
            float X = bx1 + ((float)ow + 0.25f + 0.5f * rx) * bw;
            bool vx = (X >= -1.0f) && (X <= (float)W0);
            float Xc = fminf(fmaxf(X, 0.0f), (float)(W0 - 1));
            int x0 = (int)Xc;
            float lx = Xc - (float)x0;
            float v;
            if (level == 0) {
                int y1i = min(y0 + 1, H0 - 1), x1i = min(x0 + 1, W0 - 1);
                float hy = 1.0f - ly, hx = 1.0f - lx;
                float v00 = f[y0 * W0 + x0],  v01 = f[y0 * W0 + x1i];
                float v10 = f[y1i * W0 + x0], v11 = f[y1i * W0 + x1i];
                v = hy * (hx * v00 + lx * v01) + ly * (hx * v10 + lx * v11);
            } else {
                int yb, xb; float wy[3], wxl[3];
                axis_w3_fb(y0, H0, Hc, inv_s, ly, yb, wy);
                axis_w3_fb(x0, W0, Wc, inv_s, lx, xb, wxl);
                v = 0.0f;
#pragma unroll
                for (int a = 0; a < 3; ++a) {
                    int row = min(yb + a, Hc - 1) * Wc;
                    float s = 0.0f;
#pragma unroll
                    for (int b = 0; b < 3; ++b)
                        s += wxl[b] * f[row + min(xb + b, Wc - 1)];
                    v += wy[a] * s;
                }
            }
            if (vy && vx) acc += v;
        }
    }
    out[i] = acc * 0.25f;
}

// ---------------- launch ----------------------------------------------------
extern "C" void kernel_launch(void* const* d_in, const int* in_sizes, int n_in,
                              void* d_out, int out_size, void* d_ws, size_t ws_size,
                              hipStream_t stream) {
    const float* f0    = (const float*)d_in[0];
    const float* f1    = (const float*)d_in[1];
    const float* f2    = (const float*)d_in[2];
    const float* boxes = (const float*)d_in[3];
    const int* img_h_p = (const int*)d_in[4];
    const int* img_w_p = (const int*)d_in[5];
    float* out = (float*)d_out;
    int N = in_sizes[3] / 4;

    if (ws_size >= WS_BYTES) {
        unsigned short* ws = (unsigned short*)d_ws;
        unsigned short* T0 = ws + T0_OFF;
        unsigned short* T1 = ws + T1_OFF;
        unsigned short* T2 = ws + T2_OFF;
        int n0 = ((P0 + 63) / 64) * 4;   // 3800
        int n1 = ((P1 + 63) / 64) * 4;   // 952
        int n2 = ((P2 + 63) / 64) * 4;   // 240
        transpose_all_kernel<<<n0 + n1 + n2, 256, 0, stream>>>(
            f0, f1, f2, T0, T1, T2, n0, n0 + n1);
        roi_align_cl6_kernel<<<dim3(N, 6), 256, 0, stream>>>(
            T0, T1, T2, boxes, img_h_p, img_w_p, out);
    } else {
        int total = N * CTOT * OH * OW;
        roi_align_fused_fb_kernel<<<(total + 255) / 256, 256, 0, stream>>>(
            f0, f1, f2, boxes, img_h_p, img_w_p, out, total);
    }
}

// Round 3
// 155.594 us; speedup vs baseline: 1.1424x; 1.0335x over previous
//
#include <hip/hip_runtime.h>
#include <hip/hip_fp16.h>

#define H0 200
#define W0 304
#define H1 100
#define W1 152
#define H2 50
#define W2 76
#define CPL 256   // channels per level
#define CTOT 768
#define OH 7
#define OW 7
#define NPOS 49
#define CBLK 128   // channels per stage-2 block
#define SROWP 131  // sout row stride (floats): 128 + 3 pad (131%32=3, coprime)

#define P0 (H0*W0)   // 60800
#define P1 (H1*W1)   // 15200
#define P2 (H2*W2)   // 3800
#define T0_OFF ((size_t)0)
#define T1_OFF ((size_t)P0*CPL)
#define T2_OFF ((size_t)P0*CPL + (size_t)P1*CPL)
#define WS_ELEMS ((size_t)P0*CPL + (size_t)P1*CPL + (size_t)P2*CPL)
#define WS_BYTES (WS_ELEMS * 2)   // fp16 workspace: 40,857,600 B

__device__ __forceinline__ float hat01(float d) {
    return fmaxf(0.0f, 1.0f - fabsf(d));
}

__device__ __forceinline__ unsigned short f2h_rne(float x) {
    return __half_as_ushort(__float2half_rn(x));
}

// ------------- Stage 1: fused [C][P] fp32 -> [P][C] fp16 transpose ----------
__global__ void __launch_bounds__(256)
transpose_all_kernel(const float* __restrict__ f0, const float* __restrict__ f1,
                     const float* __restrict__ f2,
                     unsigned short* __restrict__ T0,
                     unsigned short* __restrict__ T1,
                     unsigned short* __restrict__ T2, int n0, int n01) {
    __shared__ unsigned short tile[64][72];   // [p_local][c_local]
    int b = blockIdx.x;
    const float* in; unsigned short* outp; int P; int rel;
    if (b < n0)       { in = f0; outp = T0; P = P0; rel = b; }
    else if (b < n01) { in = f1; outp = T1; P = P1; rel = b - n0; }
    else              { in = f2; outp = T2; P = P2; rel = b - n01; }
    int p0 = (rel >> 2) * 64;
    int c0 = (rel & 3) * 64;

    int q = threadIdx.x & 15;     // p-quad
    int r = threadIdx.x >> 4;     // 0..15 (c)
    bool full = (p0 + 64 <= P);
#pragma unroll
    for (int i = 0; i < 4; ++i) {
        int c = c0 + r + 16 * i;
        int p = p0 + 4 * q;
        float4 v;
        if (full) {
            v = *(const float4*)(in + (size_t)c * P + p);
        } else {
            v.x = (p + 0 < P) ? in[(size_t)c * P + p + 0] : 0.0f;
            v.y = (p + 1 < P) ? in[(size_t)c * P + p + 1] : 0.0f;
            v.z = (p + 2 < P) ? in[(size_t)c * P + p + 2] : 0.0f;
            v.w = (p + 3 < P) ? in[(size_t)c * P + p + 3] : 0.0f;
        }
        tile[4 * q + 0][r + 16 * i] = f2h_rne(v.x);
        tile[4 * q + 1][r + 16 * i] = f2h_rne(v.y);
        tile[4 * q + 2][r + 16 * i] = f2h_rne(v.z);
        tile[4 * q + 3][r + 16 * i] = f2h_rne(v.w);
    }
    __syncthreads();
    int q8 = threadIdx.x & 7;     // c-octet
    int r8 = threadIdx.x >> 3;    // 0..31 (p)
#pragma unroll
    for (int i = 0; i < 2; ++i) {
        int p = p0 + r8 + 32 * i;
        if (p < P) {
            uint4 w = *(const uint4*)&tile[r8 + 32 * i][8 * q8];
            *(uint4*)(outp + (size_t)p * CPL + c0 + 8 * q8) = w;
        }
    }
}

// ------------- Stage 2: channels-last RoIAlign, 128-ch slab per block -------
// Block = (n, j), j in [0,6): level = j>>1, channel half = j&1. Each block
// computes ALL 49 positions for its 128 channels -> contiguous output slab.
// ILP fix (R3): per position, all taps of CH y-rows (12-18 loads) are issued
// into a register array BEFORE any FMA (two-phase gather-then-math), and
// addresses are 32-bit byte offsets off the uniform T base (SADDR form,
// 1 v_add per tap). launch_bounds(256,4) -> ~128 VGPR budget for the
// in-flight load array; 4 blocks/CU, 1536 blocks = 1.5 rounds (backfill).
template<int TY, int TX, int CH>
__device__ __forceinline__ void tap_loop(const char* __restrict__ Tb,
                                         const int (*__restrict__ s_idx)[6],
                                         const float (*__restrict__ s_w)[6],
                                         float (*__restrict__ sout)[SROWP],
                                         int grp, int col, unsigned laneByte) {
    for (int pos = grp; pos < NPOS; pos += 16) {
        int oh = pos / 7;
        int ow = pos - oh * 7;
        unsigned yb[TY]; float yw[TY];
#pragma unroll
        for (int j = 0; j < TY; ++j) {
            yb[j] = (unsigned)s_idx[oh][j] + laneByte;
            yw[j] = s_w[oh][j];
        }
        unsigned xb[TX]; __half2 xw2[TX];
#pragma unroll
        for (int j = 0; j < TX; ++j) {
            xb[j] = (unsigned)s_idx[7 + ow][j];
            xw2[j] = __float2half2_rn(s_w[7 + ow][j]);
        }
        float a0 = 0.f, a1 = 0.f, a2 = 0.f, a3 = 0.f;
        float a4 = 0.f, a5 = 0.f, a6 = 0.f, a7 = 0.f;
#pragma unroll
        for (int r0 = 0; r0 < TY; r0 += CH) {
            uint4 v[CH][TX];
            // phase A: issue all loads of this chunk (independent, SADDR)
#pragma unroll
            for (int r = 0; r < CH; ++r) {
                if (r0 + r < TY) {
#pragma unroll
                    for (int b = 0; b < TX; ++b)
                        v[r][b] = *(const uint4*)(Tb + (yb[r0 + r] + xb[b]));
                }
            }
            // phase B: consume
#pragma unroll
            for (int r = 0; r < CH; ++r) {
                if (r0 + r < TY) {
                    __half2 q0 = __float2half2_rn(0.0f);
                    __half2 q1 = q0, q2 = q0, q3 = q0;
#pragma unroll
                    for (int b = 0; b < TX; ++b) {
                        q0 = __hfma2(xw2[b], *(const __half2*)&v[r][b].x, q0);
                        q1 = __hfma2(xw2[b], *(const __half2*)&v[r][b].y, q1);
                        q2 = __hfma2(xw2[b], *(const __half2*)&v[r][b].z, q2);
                        q3 = __hfma2(xw2[b], *(const __half2*)&v[r][b].w, q3);
                    }
                    float wa = yw[r0 + r];
                    a0 = fmaf(wa, __low2float(q0), a0);  a1 = fmaf(wa, __high2float(q0), a1);
                    a2 = fmaf(wa, __low2float(q1), a2);  a3 = fmaf(wa, __high2float(q1), a3);
                    a4 = fmaf(wa, __low2float(q2), a4);  a5 = fmaf(wa, __high2float(q2), a5);
                    a6 = fmaf(wa, __low2float(q3), a6);  a7 = fmaf(wa, __high2float(q3), a7);
                }
            }
        }
        float4 o0, o1;
        o0.x = a0 * 0.25f; o0.y = a1 * 0.25f; o0.z = a2 * 0.25f; o0.w = a3 * 0.25f;
        o1.x = a4 * 0.25f; o1.y = a5 * 0.25f; o1.z = a6 * 0.25f; o1.w = a7 * 0.25f;
        *(float4*)(&sout[pos][col])     = o0;
        *(float4*)(&sout[pos][col + 4]) = o1;
    }
}

__global__ void __launch_bounds__(256, 4)
roi_align_cl6_kernel(const unsigned short* __restrict__ T0p,
                     const unsigned short* __restrict__ T1p,
                     const unsigned short* __restrict__ T2p,
                     const float* __restrict__ boxes,
                     const int* __restrict__ img_h_p,
                     const int* __restrict__ img_w_p,
                     float* __restrict__ out) {
    __shared__ float sout[NPOS][SROWP];    // [pos][c_local]
    __shared__ int   s_idx[14][6];         // BYTE offsets: [0..6]=y(oh), [7..13]=x(ow)
    __shared__ float s_w[14][6];

    const int n = blockIdx.x;
    const int j = blockIdx.y;              // 0..5
    const int lev = j >> 1;
    const int chalf = j & 1;
    const int tid = threadIdx.x;

    const unsigned short* T; int Hc, Wc; float inv_s;
    if (lev == 0)      { T = T0p; Hc = H0; Wc = W0; inv_s = 1.0f;  }
    else if (lev == 1) { T = T1p; Hc = H1; Wc = W1; inv_s = 0.5f;  }
    else               { T = T2p; Hc = H2; Wc = W2; inv_s = 0.25f; }

    if (tid < 14) {
        int axis = (tid >= 7) ? 1 : 0;     // 0 = y, 1 = x
        int o = tid - axis * 7;
        float sx = (float)W0 / (float)img_w_p[0];
        float sy = (float)H0 / (float)img_h_p[0];
        float a1v, bs; int Hf, Hca, mul;
        if (axis) {
            a1v = boxes[n * 4 + 0] * sx;
            float a2v = boxes[n * 4 + 2] * sx;
            bs = fmaxf(a2v - a1v, 1.0f) * (1.0f / (float)OW);
            Hf = W0; Hca = Wc; mul = 1;
        } else {
            a1v = boxes[n * 4 + 1] * sy;
            float a2v = boxes[n * 4 + 3] * sy;
            bs = fmaxf(a2v - a1v, 1.0f) * (1.0f / (float)OH);
            Hf = H0; Hca = Hc; mul = Wc;
        }
        int idx[6]; float w[6];
#pragma unroll
        for (int t = 0; t < 6; ++t) { idx[t] = 0; w[t] = 0.0f; }
        if (lev == 0) {
#pragma unroll
            for (int r2 = 0; r2 < 2; ++r2) {
                float Y = a1v + ((float)o + 0.25f + 0.5f * (float)r2) * bs;
                float v = (Y >= -1.0f && Y <= (float)Hf) ? 1.0f : 0.0f;
                float Yc = fminf(fmaxf(Y, 0.0f), (float)(Hf - 1));
                int y0 = (int)Yc; float lf = Yc - (float)y0;
                idx[2 * r2]     = y0;                  w[2 * r2]     = (1.0f - lf) * v;
                idx[2 * r2 + 1] = min(y0 + 1, Hf - 1); w[2 * r2 + 1] = lf * v;
            }
        } else {
            int bases[2]; float w3[2][3];
#pragma unroll
            for (int r2 = 0; r2 < 2; ++r2) {
                float Y = a1v + ((float)o + 0.25f + 0.5f * (float)r2) * bs;
                float v = (Y >= -1.0f && Y <= (float)Hf) ? 1.0f : 0.0f;
                float Yc = fminf(fmaxf(Y, 0.0f), (float)(Hf - 1));
                int y0 = (int)Yc; float lf = Yc - (float)y0; float hf = 1.0f - lf;
                int yf1 = min(y0 + 1, Hf - 1);
                float yc0 = fminf(fmaxf(((float)y0 + 0.5f) * inv_s - 0.5f, 0.0f), (float)(Hca - 1));
                float yc1 = fminf(fmaxf(((float)yf1 + 0.5f) * inv_s - 0.5f, 0.0f), (float)(Hca - 1));
                int b2 = (int)yc0;
                bases[r2] = b2;
#pragma unroll
                for (int t2 = 0; t2 < 3; ++t2) {
                    float j2 = (float)(b2 + t2);
                    w3[r2][t2] = v * (hf * hat01(yc0 - j2) + lf * hat01(yc1 - j2));
                }
            }
            int dmax = (lev == 1) ? 3 : 2;   // geometry: box<=272px -> gap<=2.43/1.21
            int d = min(max(bases[1] - bases[0], 0), dmax);
            w[0] += w3[0][0]; w[1] += w3[0][1]; w[2] += w3[0][2];
            w[d] += w3[1][0]; w[d + 1] += w3[1][1]; w[d + 2] += w3[1][2];
#pragma unroll
            for (int t = 0; t < 6; ++t) idx[t] = min(bases[0] + t, Hca - 1);
        }
        // pre-scale to BYTE offset in T (row stride Wc*CPL elems, 2B/elem)
#pragma unroll
        for (int t = 0; t < 6; ++t) { s_idx[tid][t] = idx[t] * mul * CPL * 2; s_w[tid][t] = w[t]; }
    }
    __syncthreads();

    const int grp = tid >> 4;              // 0..15: position group
    const int l16 = tid & 15;              // 0..15: 8 channels each
    const int col = l16 * 8;               // local channel within the 128-slab
    const unsigned laneByte = (unsigned)(chalf * CBLK + col) * 2u;
    const char* Tb = (const char*)T;       // uniform base -> SADDR loads

    if (lev == 0)      tap_loop<4, 4, 4>(Tb, s_idx, s_w, sout, grp, col, laneByte);
    else if (lev == 1) tap_loop<6, 6, 3>(Tb, s_idx, s_w, sout, grp, col, laneByte);
    else               tap_loop<5, 5, 3>(Tb, s_idx, s_w, sout, grp, col, laneByte);
    __syncthreads();

    // Writeback: out[n][lev*256 + chalf*128 + c][p], contiguous 128*49 floats.
    size_t obase = (size_t)n * CTOT * NPOS + (size_t)(lev * CPL + chalf * CBLK) * NPOS;
    int c = tid / NPOS;
    int p = tid - c * NPOS;
    for (int i = tid; i < CBLK * NPOS; i += 256) {
        out[obase + i] = sout[p][c];
        c += 5; p += 11;                   // 256 = 5*49 + 11
        if (p >= NPOS) { p -= NPOS; ++c; }
    }
}

// ---------------- Fallback (R1 kernel) if ws too small ----------------------
__device__ __forceinline__ void axis_w3_fb(int yf0, int Hf, int Hc, float inv_s,
                                           float lf, int& base, float* w) {
    int yf1 = min(yf0 + 1, Hf - 1);
    float hf = 1.0f - lf;
    float yc0 = fminf(fmaxf(((float)yf0 + 0.5f) * inv_s - 0.5f, 0.0f), (float)(Hc - 1));
    float yc1 = fminf(fmaxf(((float)yf1 + 0.5f) * inv_s - 0.5f, 0.0f), (float)(Hc - 1));
    base = (int)yc0;
#pragma unroll
    for (int r = 0; r < 3; ++r) {
        float j = (float)(base + r);
        w[r] = hf * hat01(yc0 - j) + lf * hat01(yc1 - j);
    }
}

__global__ void __launch_bounds__(256)
roi_align_fused_fb_kernel(const float* __restrict__ f0,
                          const float* __restrict__ f1,
                          const float* __restrict__ f2,
                          const float* __restrict__ boxes,
                          const int* __restrict__ img_h_p,
                          const int* __restrict__ img_w_p,
                          float* __restrict__ out,
                          int total) {
    int i = blockIdx.x * blockDim.x + threadIdx.x;
    if (i >= total) return;
    int ow = i % OW;
    int t = i / OW;
    int oh = t % OH; t /= OH;
    int c = t % CTOT;
    int n = t / CTOT;
    float sx = (float)W0 / (float)img_w_p[0];
    float sy = (float)H0 / (float)img_h_p[0];
    float bx1 = boxes[n * 4 + 0] * sx;
    float by1 = boxes[n * 4 + 1] * sy;
    float bw = fmaxf(boxes[n * 4 + 2] * sx - bx1, 1.0f) / OW;
    float bh = fmaxf(boxes[n * 4 + 3] * sy - by1, 1.0f) / OH;
    int level = c >> 8;
    int cl = c & (CPL - 1);
    const float* f;
    int Hc, Wc; float inv_s;
    if (level == 0)      { f = f0 + (size_t)cl * P0; Hc = H0; Wc = W0; inv_s = 1.0f;  }
    else if (level == 1) { f = f1 + (size_t)cl * P1; Hc = H1; Wc = W1; inv_s = 0.5f;  }
    else                 { f = f2 + (size_t)cl * P2; Hc = H2; Wc = W2; inv_s = 0.25f; }
    float acc = 0.0f;
#pragma unroll
    for (int ry = 0; ry < 2; ++ry) {
        float Y = by1 + ((float)oh + 0.25f + 0.5f * ry) * bh;
        bool vy = (Y >= -1.0f) && (Y <= (float)H0);
        float Yc = fminf(fmaxf(Y, 0.0f), (float)(H0 - 1));
        int y0 = (int)Yc;
        float ly = Yc - (float)y0;
#pragma unroll
        for (int rx = 0; rx < 2; ++rx) {
            float X = bx1 + ((float)ow + 0.25f + 0.5f * rx) * bw;
            bool vx = (X >= -1.0f) && (X <= (float)W0);
            float Xc = fminf(fmaxf(X, 0.0f), (float)(W0 - 1));
            int x0 = (int)Xc;
            float lx = Xc - (float)x0;
            float v;
            if (level == 0) {
                int y1i = min(y0 + 1, H0 - 1), x1i = min(x0 + 1, W0 - 1);
                float hy = 1.0f - ly, hx = 1.0f - lx;
                float v00 = f[y0 * W0 + x0],  v01 = f[y0 * W0 + x1i];
                float v10 = f[y1i * W0 + x0], v11 = f[y1i * W0 + x1i];
                v = hy * (hx * v00 + lx * v01) + ly * (hx * v10 + lx * v11);
            } else {
                int yb, xb; float wy[3], wxl[3];
                axis_w3_fb(y0, H0, Hc, inv_s, ly, yb, wy);
                axis_w3_fb(x0, W0, Wc, inv_s, lx, xb, wxl);
                v = 0.0f;
#pragma unroll
                for (int a = 0; a < 3; ++a) {
                    int row = min(yb + a, Hc - 1) * Wc;
                    float s = 0.0f;
#pragma unroll
                    for (int b = 0; b < 3; ++b)
                        s += wxl[b] * f[row + min(xb + b, Wc - 1)];
                    v += wy[a] * s;
                }
            }
            if (vy && vx) acc += v;
        }
    }
    out[i] = acc * 0.25f;
}

// ---------------- launch ----------------------------------------------------
extern "C" void kernel_launch(void* const* d_in, const int* in_sizes, int n_in,
                              void* d_out, int out_size, void* d_ws, size_t ws_size,
                              hipStream_t stream) {
    const float* f0    = (const float*)d_in[0];
    const float* f1    = (const float*)d_in[1];
    const float* f2    = (const float*)d_in[2];
    const float* boxes = (const float*)d_in[3];
    const int* img_h_p = (const int*)d_in[4];
    const int* img_w_p = (const int*)d_in[5];
    float* out = (float*)d_out;
    int N = in_sizes[3] / 4;

    if (ws_size >= WS_BYTES) {
        unsigned short* ws = (unsigned short*)d_ws;
        unsigned short* T0 = ws + T0_OFF;
        unsigned short* T1 = ws + T1_OFF;
        unsigned short* T2 = ws + T2_OFF;
        int n0 = ((P0 + 63) / 64) * 4;   // 3800
        int n1 = ((P1 + 63) / 64) * 4;   // 952
        int n2 = ((P2 + 63) / 64) * 4;   // 240
        transpose_all_kernel<<<n0 + n1 + n2, 256, 0, stream>>>(
            f0, f1, f2, T0, T1, T2, n0, n0 + n1);
        roi_align_cl6_kernel<<<dim3(N, 6), 256, 0, stream>>>(
            T0, T1, T2, boxes, img_h_p, img_w_p, out);
    } else {
        int total = N * CTOT * OH * OW;
        roi_align_fused_fb_kernel<<<(total + 255) / 256, 256, 0, stream>>>(
            f0, f1, f2, boxes, img_h_p, img_w_p, out, total);
    }
}